// Round 1
// baseline (249.449 us; speedup 1.0000x reference)
//
#include <hip/hip_runtime.h>
#include <hip/hip_bf16.h>
#include <math.h>

#define BATCH 8
#define SEQ   2048
#define CDIM  1024
#define HD    64
#define LOG2E 1.4426950408889634f

// ---------------- kernel 1: K = x @ W_k^T  ([B*T,1024] x [64,1024]^T -> [B*T,64]) ----
// block: 256 threads, computes 64 rows x 64 heads. Loops C in chunks of 128.
// LDS tiles XOR-swizzled so the strided ds_read_b128 in the inner loop are ~conflict-free.
__global__ __launch_bounds__(256) void proj_kernel(const float* __restrict__ x,
                                                   const float* __restrict__ Wk,
                                                   float* __restrict__ Kp) {
    __shared__ float xs[64][128];
    __shared__ float wsh[64][128];
    const int tid = threadIdx.x;
    const int tx = tid & 15, ty = tid >> 4;
    const size_t row0 = (size_t)blockIdx.x * 64;

    float acc[4][4] = {};

    for (int c0 = 0; c0 < CDIM; c0 += 128) {
        // cooperative stage: 64 rows x 128 cols (x) and 64 heads x 128 cols (W)
        #pragma unroll
        for (int k = 0; k < 8; ++k) {
            int f  = tid + k * 256;        // float4 slot 0..2047
            int r  = f >> 5;               // row/head 0..63
            int cc = (f & 31) << 2;        // col 0..124 step 4
            int pc = cc ^ (((r >> 2) & 7) << 2);   // XOR swizzle (16B granular)
            float4 xv = *(const float4*)(x  + (row0 + r) * CDIM + c0 + cc);
            float4 wv = *(const float4*)(Wk + (size_t)r * CDIM + c0 + cc);
            *(float4*)(&xs[r][pc])  = xv;
            *(float4*)(&wsh[r][pc]) = wv;
        }
        __syncthreads();
        #pragma unroll 4
        for (int c4 = 0; c4 < 128; c4 += 4) {
            float4 a[4], w[4];
            #pragma unroll
            for (int i = 0; i < 4; ++i) {
                int r = ty * 4 + i;
                a[i] = *(const float4*)(&xs[r][c4 ^ (((r >> 2) & 7) << 2)]);
            }
            #pragma unroll
            for (int j = 0; j < 4; ++j) {
                int h = tx * 4 + j;
                w[j] = *(const float4*)(&wsh[h][c4 ^ (((h >> 2) & 7) << 2)]);
            }
            #pragma unroll
            for (int i = 0; i < 4; ++i)
                #pragma unroll
                for (int j = 0; j < 4; ++j)
                    acc[i][j] += a[i].x * w[j].x + a[i].y * w[j].y +
                                 a[i].z * w[j].z + a[i].w * w[j].w;
        }
        __syncthreads();
    }
    #pragma unroll
    for (int i = 0; i < 4; ++i) {
        float4 v = make_float4(acc[i][0], acc[i][1], acc[i][2], acc[i][3]);
        *(float4*)(Kp + (row0 + ty * 4 + i) * HD + tx * 4) = v;
    }
}

// ---------------- kernel 2: causal flash attention with Q=K=V=Kp --------------------
// block: 256 threads = 4 waves; block owns 64 q-rows (lane = q-row).
// Each wave processes key-tiles t = wid, wid+4, ... (private LDS region -> no barrier
// in the main loop), keeping (m, l, o[64]) online-softmax state in registers.
// Partials are combined across the 4 waves through LDS at the end.
__global__ __launch_bounds__(256, 1) void attn_kernel(const float* __restrict__ Kp,
                                                      float* __restrict__ out) {
    __shared__ float Ks[4][64][68];   // per-wave staging; reused for o-partials
    __shared__ float Pm[4][64];
    __shared__ float Pl[4][64];

    const int tid  = threadIdx.x;
    const int wid  = tid >> 6;
    const int lane = tid & 63;
    const int blk  = blockIdx.x;
    const int b    = blk >> 5;       // batch
    const int qt   = blk & 31;       // q tile (64 rows)
    const int q0   = qt * 64;
    const int qrow = q0 + lane;

    const float* Kb = Kp + (size_t)b * SEQ * HD;

    float4 q4[16], o4[16];
    #pragma unroll
    for (int d4 = 0; d4 < 16; ++d4) {
        q4[d4] = *(const float4*)(Kb + (size_t)qrow * HD + d4 * 4);
        o4[d4] = make_float4(0.f, 0.f, 0.f, 0.f);
    }
    float m = -INFINITY, l = 0.f;

    for (int t = wid; t <= qt; t += 4) {
        // stage key tile t (64 keys x 64 dims) into this wave's private region
        const float* src = Kb + (size_t)t * 64 * HD;
        #pragma unroll
        for (int k = 0; k < 16; ++k) {
            int f  = lane + k * 64;     // float4 slot 0..1023
            int r  = f >> 4;
            int cc = (f & 15) << 2;
            *(float4*)(&Ks[wid][r][cc]) = *(const float4*)(src + r * HD + cc);
        }
        const int kbase = t * 64;
        #pragma unroll 1
        for (int j = 0; j < 64; ++j) {
            float4 kv[16];
            #pragma unroll
            for (int d4 = 0; d4 < 16; ++d4)
                kv[d4] = *(const float4*)(&Ks[wid][j][d4 * 4]);
            float s = 0.f;
            #pragma unroll
            for (int d4 = 0; d4 < 16; ++d4)
                s += q4[d4].x * kv[d4].x + q4[d4].y * kv[d4].y +
                     q4[d4].z * kv[d4].z + q4[d4].w * kv[d4].w;
            s *= 0.03125f;   // C^-0.5 = 1/32
            if (kbase + j <= qrow) {
                if (s > m) {
                    float al = __builtin_amdgcn_exp2f((m - s) * LOG2E);
                    l *= al;
                    #pragma unroll
                    for (int d4 = 0; d4 < 16; ++d4) {
                        o4[d4].x *= al; o4[d4].y *= al;
                        o4[d4].z *= al; o4[d4].w *= al;
                    }
                    m = s;
                }
                float p = __builtin_amdgcn_exp2f((s - m) * LOG2E);
                l += p;
                #pragma unroll
                for (int d4 = 0; d4 < 16; ++d4) {
                    o4[d4].x += p * kv[d4].x; o4[d4].y += p * kv[d4].y;
                    o4[d4].z += p * kv[d4].z; o4[d4].w += p * kv[d4].w;
                }
            }
        }
    }

    // publish partials (own region only -> no cross-wave hazard before barrier)
    #pragma unroll
    for (int d4 = 0; d4 < 16; ++d4)
        *(float4*)(&Ks[wid][lane][d4 * 4]) = o4[d4];
    Pm[wid][lane] = m;
    Pl[wid][lane] = l;
    __syncthreads();

    // combine 4 partials per row; 4 threads per row split the 64 dims
    const int r = tid & 63;
    const int g = tid >> 6;
    float m0 = Pm[0][r], m1 = Pm[1][r], m2 = Pm[2][r], m3 = Pm[3][r];
    float mr = fmaxf(fmaxf(m0, m1), fmaxf(m2, m3));
    float c0 = __builtin_amdgcn_exp2f((m0 - mr) * LOG2E);
    float c1 = __builtin_amdgcn_exp2f((m1 - mr) * LOG2E);
    float c2 = __builtin_amdgcn_exp2f((m2 - mr) * LOG2E);
    float c3 = __builtin_amdgcn_exp2f((m3 - mr) * LOG2E);
    float Lr = Pl[0][r] * c0 + Pl[1][r] * c1 + Pl[2][r] * c2 + Pl[3][r] * c3;
    float inv = 1.f / Lr;
    c0 *= inv; c1 *= inv; c2 *= inv; c3 *= inv;
    #pragma unroll
    for (int d4 = g * 4; d4 < g * 4 + 4; ++d4) {
        float4 v0 = *(const float4*)(&Ks[0][r][d4 * 4]);
        float4 v1 = *(const float4*)(&Ks[1][r][d4 * 4]);
        float4 v2 = *(const float4*)(&Ks[2][r][d4 * 4]);
        float4 v3 = *(const float4*)(&Ks[3][r][d4 * 4]);
        float4 acc;
        acc.x = c0 * v0.x + c1 * v1.x + c2 * v2.x + c3 * v3.x;
        acc.y = c0 * v0.y + c1 * v1.y + c2 * v2.y + c3 * v3.y;
        acc.z = c0 * v0.z + c1 * v1.z + c2 * v2.z + c3 * v3.z;
        acc.w = c0 * v0.w + c1 * v1.w + c2 * v2.w + c3 * v3.w;
        *(float4*)(out + ((size_t)b * SEQ + q0 + r) * HD + d4 * 4) = acc;
    }
}

extern "C" void kernel_launch(void* const* d_in, const int* in_sizes, int n_in,
                              void* d_out, int out_size, void* d_ws, size_t ws_size,
                              hipStream_t stream) {
    const float* x  = (const float*)d_in[0];   // [8,2048,1024] fp32
    const float* Wk = (const float*)d_in[1];   // [64,1024] fp32
    float* o        = (float*)d_out;           // [8,2048,64] fp32
    float* Kp       = (float*)d_ws;            // [8*2048,64] fp32 scratch (4 MB)

    proj_kernel<<<(BATCH * SEQ) / 64, 256, 0, stream>>>(x, Wk, Kp);
    attn_kernel<<<BATCH * (SEQ / 64), 256, 0, stream>>>(Kp, o);
}

// Round 2
// 140.860 us; speedup vs baseline: 1.7709x; 1.7709x over previous
//
#include <hip/hip_runtime.h>
#include <hip/hip_bf16.h>
#include <math.h>

#define SEQ  2048
#define CDIM 1024
#define HD   64
// log2(e)/32  (softmax scale C^-0.5 = 1/32 folded into the exp2 multiplier)
#define CEXP 0.04508422002778112f

typedef float  f32x4  __attribute__((ext_vector_type(4)));
typedef __bf16 bf16x8 __attribute__((ext_vector_type(8)));
typedef int    i32x4  __attribute__((ext_vector_type(4)));

// RNE-pack two f32 into one dword of 2 bf16
static __device__ __forceinline__ unsigned pk2(float a, float b) {
    unsigned ua = __builtin_bit_cast(unsigned, a);
    unsigned ub = __builtin_bit_cast(unsigned, b);
    ua += 0x7fffu + ((ua >> 16) & 1u);
    ub += 0x7fffu + ((ub >> 16) & 1u);
    return (ua >> 16) | (ub & 0xffff0000u);
}

static __device__ __forceinline__ bf16x8 cvt8(float4 lo, float4 hi) {
    i32x4 w = { (int)pk2(lo.x, lo.y), (int)pk2(lo.z, lo.w),
                (int)pk2(hi.x, hi.y), (int)pk2(hi.z, hi.w) };
    return __builtin_bit_cast(bf16x8, w);
}

// ---------------- kernel 1: K = x @ W_k^T -> bf16 [16384][64] -------------------
// 512 blocks x 64 threads (1 wave). Wave: M=32 rows x N=64 heads, K-loop 32 steps of 32.
// No LDS: MFMA fragments come straight from global (x: HBM stream, W: L2-resident).
__global__ __launch_bounds__(64) void proj_kernel(const float* __restrict__ x,
                                                  const float* __restrict__ Wk,
                                                  unsigned short* __restrict__ Ko) {
    const int l = threadIdx.x, lm = l & 15, lg = l >> 4;
    const size_t m0 = (size_t)blockIdx.x * 32;
    f32x4 acc[2][4];
    #pragma unroll
    for (int i = 0; i < 2; ++i)
        #pragma unroll
        for (int j = 0; j < 4; ++j) acc[i][j] = (f32x4){0.f, 0.f, 0.f, 0.f};

    const float* xr0 = x + (m0 + lm) * CDIM + lg * 8;        // A-frag row, M-tile 0
    const float* xr1 = x + (m0 + 16 + lm) * CDIM + lg * 8;   // M-tile 1
    const float* wr  = Wk + (size_t)lm * CDIM + lg * 8;      // B-frag row (head lm)

    #pragma unroll 2
    for (int ks = 0; ks < 32; ++ks) {
        const int ko = ks * 32;
        float4 a0l = *(const float4*)(xr0 + ko), a0h = *(const float4*)(xr0 + ko + 4);
        float4 a1l = *(const float4*)(xr1 + ko), a1h = *(const float4*)(xr1 + ko + 4);
        bf16x8 A0 = cvt8(a0l, a0h), A1 = cvt8(a1l, a1h);
        #pragma unroll
        for (int nt = 0; nt < 4; ++nt) {
            const float* wp = wr + (size_t)(nt * 16) * CDIM + ko;
            float4 bl = *(const float4*)wp, bh = *(const float4*)(wp + 4);
            bf16x8 B = cvt8(bl, bh);
            acc[0][nt] = __builtin_amdgcn_mfma_f32_16x16x32_bf16(A0, B, acc[0][nt], 0, 0, 0);
            acc[1][nt] = __builtin_amdgcn_mfma_f32_16x16x32_bf16(A1, B, acc[1][nt], 0, 0, 0);
        }
    }
    // D layout: col = lm (head-local), row = lg*4 + r (M-local)
    #pragma unroll
    for (int mt = 0; mt < 2; ++mt)
        #pragma unroll
        for (int nt = 0; nt < 4; ++nt)
            #pragma unroll
            for (int r = 0; r < 4; ++r) {
                unsigned p = pk2(acc[mt][nt][r], 0.f) & 0xffffu;
                Ko[(m0 + mt * 16 + lg * 4 + r) * HD + nt * 16 + lm] = (unsigned short)p;
            }
}

// ---------------- kernel 2: causal flash attention, Q=K=V, MFMA -----------------
struct KT { bf16x8 ka0, ka1, bv0, bv1, bv2, bv3; };

static __device__ __forceinline__ KT load_tile(const unsigned short* __restrict__ Kb,
                                               int kt, int lm, int lg) {
    KT t;
    // QK A-frag (swapped): row = kv-local = lm, k = d = lg*8 + j (+32 for frag 1)
    const unsigned short* ar = Kb + (size_t)(kt * 16 + lm) * HD + lg * 8;
    t.ka0 = *(const bf16x8*)ar;
    t.ka1 = *(const bf16x8*)(ar + 32);
    // PV B-frags: col = d-local = lm (+16n), k-slot j<4 -> kv = lg*4 + j; upper half zero
    const unsigned short* vr = Kb + (size_t)(kt * 16 + lg * 4) * HD + lm;
    {
        unsigned v0 = vr[0], v1 = vr[64], v2 = vr[128], v3 = vr[192];
        i32x4 w = { (int)(v0 | (v1 << 16)), (int)(v2 | (v3 << 16)), 0, 0 };
        t.bv0 = __builtin_bit_cast(bf16x8, w);
    }
    {
        unsigned v0 = vr[16], v1 = vr[80], v2 = vr[144], v3 = vr[208];
        i32x4 w = { (int)(v0 | (v1 << 16)), (int)(v2 | (v3 << 16)), 0, 0 };
        t.bv1 = __builtin_bit_cast(bf16x8, w);
    }
    {
        unsigned v0 = vr[32], v1 = vr[96], v2 = vr[160], v3 = vr[224];
        i32x4 w = { (int)(v0 | (v1 << 16)), (int)(v2 | (v3 << 16)), 0, 0 };
        t.bv2 = __builtin_bit_cast(bf16x8, w);
    }
    {
        unsigned v0 = vr[48], v1 = vr[112], v2 = vr[176], v3 = vr[240];
        i32x4 w = { (int)(v0 | (v1 << 16)), (int)(v2 | (v3 << 16)), 0, 0 };
        t.bv3 = __builtin_bit_cast(bf16x8, w);
    }
    return t;
}

template <bool DIAG>
static __device__ __forceinline__ void proc_tile(const KT& t, bf16x8 bq0, bf16x8 bq1,
                                                 int lm, int lg,
                                                 float& m, float& ls, f32x4 o[4]) {
    f32x4 s4 = (f32x4){0.f, 0.f, 0.f, 0.f};
    s4 = __builtin_amdgcn_mfma_f32_16x16x32_bf16(t.ka0, bq0, s4, 0, 0, 0);
    s4 = __builtin_amdgcn_mfma_f32_16x16x32_bf16(t.ka1, bq1, s4, 0, 0, 0);
    // D: col = lm = q-local, row = lg*4 + r = kv-local   (raw scores, unscaled)
    float s0 = s4[0], s1 = s4[1], s2 = s4[2], s3 = s4[3];
    if (DIAG) {
        const int kb = lg * 4;
        s0 = (kb + 0 > lm) ? -1e30f : s0;
        s1 = (kb + 1 > lm) ? -1e30f : s1;
        s2 = (kb + 2 > lm) ? -1e30f : s2;
        s3 = (kb + 3 > lm) ? -1e30f : s3;
    }
    float pm = fmaxf(fmaxf(s0, s1), fmaxf(s2, s3));
    pm = fmaxf(pm, __shfl_xor(pm, 16));
    pm = fmaxf(pm, __shfl_xor(pm, 32));
    if (__any(pm > m + 256.f)) {   // defer-max: 256 raw = 8 e-folds after scaling
        float mn = fmaxf(m, pm);
        float al = __builtin_amdgcn_exp2f((m - mn) * CEXP);
        m = mn;
        ls *= al;
        float a0 = __shfl(al, lg * 4 + 0);
        float a1 = __shfl(al, lg * 4 + 1);
        float a2 = __shfl(al, lg * 4 + 2);
        float a3 = __shfl(al, lg * 4 + 3);
        #pragma unroll
        for (int n = 0; n < 4; ++n) {
            o[n][0] *= a0; o[n][1] *= a1; o[n][2] *= a2; o[n][3] *= a3;
        }
    }
    const float mC = m * CEXP;
    float p0 = __builtin_amdgcn_exp2f(s0 * CEXP - mC);
    float p1 = __builtin_amdgcn_exp2f(s1 * CEXP - mC);
    float p2 = __builtin_amdgcn_exp2f(s2 * CEXP - mC);
    float p3 = __builtin_amdgcn_exp2f(s3 * CEXP - mC);
    ls += (p0 + p1) + (p2 + p3);
    // P^T A-frag: row = q = lm, k-slot j<4 -> kv = lg*4 + j (matches D rows exactly)
    i32x4 pw = { (int)pk2(p0, p1), (int)pk2(p2, p3), 0, 0 };
    bf16x8 pa = __builtin_bit_cast(bf16x8, pw);
    o[0] = __builtin_amdgcn_mfma_f32_16x16x32_bf16(pa, t.bv0, o[0], 0, 0, 0);
    o[1] = __builtin_amdgcn_mfma_f32_16x16x32_bf16(pa, t.bv1, o[1], 0, 0, 0);
    o[2] = __builtin_amdgcn_mfma_f32_16x16x32_bf16(pa, t.bv2, o[2], 0, 0, 0);
    o[3] = __builtin_amdgcn_mfma_f32_16x16x32_bf16(pa, t.bv3, o[3], 0, 0, 0);
}

static __device__ __forceinline__ void do_qtile(const unsigned short* __restrict__ Kb,
                                                float* __restrict__ ob,
                                                int qt, int lm, int lg) {
    const unsigned short* qr = Kb + (size_t)(qt * 16 + lm) * HD + lg * 8;
    bf16x8 bq0 = *(const bf16x8*)qr;          // B-frag: col = q-local = lm, k = d
    bf16x8 bq1 = *(const bf16x8*)(qr + 32);
    float m = -INFINITY, ls = 0.f;
    f32x4 o[4];
    o[0] = o[1] = o[2] = o[3] = (f32x4){0.f, 0.f, 0.f, 0.f};

    KT A = load_tile(Kb, 0, lm, lg);
    int kt = 0;
    while (kt + 1 < qt) {                     // software-pipelined full tiles
        KT B = load_tile(Kb, kt + 1, lm, lg);
        proc_tile<false>(A, bq0, bq1, lm, lg, m, ls, o);
        A = load_tile(Kb, kt + 2, lm, lg);    // kt+2 <= qt guaranteed
        proc_tile<false>(B, bq0, bq1, lm, lg, m, ls, o);
        kt += 2;
    }
    if (kt < qt) {
        KT B = load_tile(Kb, kt + 1, lm, lg);
        proc_tile<false>(A, bq0, bq1, lm, lg, m, ls, o);
        proc_tile<true>(B, bq0, bq1, lm, lg, m, ls, o);
    } else {
        proc_tile<true>(A, bq0, bq1, lm, lg, m, ls, o);
    }

    ls += __shfl_xor(ls, 16);
    ls += __shfl_xor(ls, 32);
    float inv = 1.0f / ls;
    float i0 = __shfl(inv, lg * 4 + 0);
    float i1 = __shfl(inv, lg * 4 + 1);
    float i2 = __shfl(inv, lg * 4 + 2);
    float i3 = __shfl(inv, lg * 4 + 3);
    // O D-layout: col = lm = d-local (per n-tile), row = lg*4 + r = q-local
    #pragma unroll
    for (int n = 0; n < 4; ++n) {
        float* op = ob + (size_t)(qt * 16) * HD + n * 16 + lm;
        op[(lg * 4 + 0) * HD] = o[n][0] * i0;
        op[(lg * 4 + 1) * HD] = o[n][1] * i1;
        op[(lg * 4 + 2) * HD] = o[n][2] * i2;
        op[(lg * 4 + 3) * HD] = o[n][3] * i3;
    }
}

// 512 blocks x 64 threads: block = (batch, pair i) -> q-tiles {i, 127-i}: 129 kv-tiles each.
__global__ __launch_bounds__(64) void attn_kernel(const unsigned short* __restrict__ K,
                                                  float* __restrict__ out) {
    const int l = threadIdx.x, lm = l & 15, lg = l >> 4;
    const int b = blockIdx.x >> 6;
    const int i = blockIdx.x & 63;
    const unsigned short* Kb = K + (size_t)b * SEQ * HD;
    float* ob = out + (size_t)b * SEQ * HD;
    do_qtile(Kb, ob, i, lm, lg);
    do_qtile(Kb, ob, 127 - i, lm, lg);
}

extern "C" void kernel_launch(void* const* d_in, const int* in_sizes, int n_in,
                              void* d_out, int out_size, void* d_ws, size_t ws_size,
                              hipStream_t stream) {
    const float* x  = (const float*)d_in[0];   // [8,2048,1024] fp32
    const float* Wk = (const float*)d_in[1];   // [64,1024] fp32
    float* o        = (float*)d_out;           // [8,2048,64] fp32
    unsigned short* Kp = (unsigned short*)d_ws; // K as bf16 [16384][64] (2 MB)

    proj_kernel<<<512, 64, 0, stream>>>(x, Wk, Kp);
    attn_kernel<<<512, 64, 0, stream>>>(Kp, o);
}

// Round 4
// 60.307 us; speedup vs baseline: 4.1363x; 2.3357x over previous
//
#include <hip/hip_runtime.h>
#include <hip/hip_bf16.h>
#include <math.h>

#define SEQ  2048
#define CDIM 1024
#define HD   64
// log2(e)/32  (softmax scale C^-0.5 = 1/32 folded into the exp2 multiplier)
#define CEXP 0.04508422002778112f

typedef float  f32x4  __attribute__((ext_vector_type(4)));
typedef __bf16 bf16x8 __attribute__((ext_vector_type(8)));
typedef int    i32x4  __attribute__((ext_vector_type(4)));

// RNE-pack two f32 into one dword of 2 bf16
static __device__ __forceinline__ unsigned pk2(float a, float b) {
    unsigned ua = __builtin_bit_cast(unsigned, a);
    unsigned ub = __builtin_bit_cast(unsigned, b);
    ua += 0x7fffu + ((ua >> 16) & 1u);
    ub += 0x7fffu + ((ub >> 16) & 1u);
    return (ua >> 16) | (ub & 0xffff0000u);
}

static __device__ __forceinline__ bf16x8 cvt8(float4 lo, float4 hi) {
    i32x4 w = { (int)pk2(lo.x, lo.y), (int)pk2(lo.z, lo.w),
                (int)pk2(hi.x, hi.y), (int)pk2(hi.z, hi.w) };
    return __builtin_bit_cast(bf16x8, w);
}

// ---------------- kernel 0: W fp32 -> bf16 (one-shot, 128 KB) -------------------
__global__ __launch_bounds__(256) void wconv_kernel(const float* __restrict__ W,
                                                    unsigned* __restrict__ Wb) {
    const int i = blockIdx.x * 256 + threadIdx.x;   // 16384 threads x 4 floats
    float4 v = *(const float4*)(W + (size_t)i * 4);
    uint2 p = make_uint2(pk2(v.x, v.y), pk2(v.z, v.w));
    *(uint2*)(Wb + (size_t)i * 2) = p;
}

// ---------------- kernel 1: K = x @ W_k^T -> bf16 [16384][64] -------------------
// 1024 blocks x 64 threads (1 wave), M=16/wave. Register-rotated pipeline, depth 2.
struct PF { float4 al, ah; bf16x8 b0, b1, b2, b3; };

static __device__ __forceinline__ PF pload(const float* __restrict__ xr,
                                           const unsigned short* __restrict__ wr, int ks) {
    PF f;
    f.al = *(const float4*)(xr + ks * 32);
    f.ah = *(const float4*)(xr + ks * 32 + 4);
    f.b0 = *(const bf16x8*)(wr + ks * 32);
    f.b1 = *(const bf16x8*)(wr + 16 * CDIM + ks * 32);
    f.b2 = *(const bf16x8*)(wr + 32 * CDIM + ks * 32);
    f.b3 = *(const bf16x8*)(wr + 48 * CDIM + ks * 32);
    return f;
}

static __device__ __forceinline__ void pstep(const PF& f, f32x4 acc[4]) {
    bf16x8 A = cvt8(f.al, f.ah);
    acc[0] = __builtin_amdgcn_mfma_f32_16x16x32_bf16(A, f.b0, acc[0], 0, 0, 0);
    acc[1] = __builtin_amdgcn_mfma_f32_16x16x32_bf16(A, f.b1, acc[1], 0, 0, 0);
    acc[2] = __builtin_amdgcn_mfma_f32_16x16x32_bf16(A, f.b2, acc[2], 0, 0, 0);
    acc[3] = __builtin_amdgcn_mfma_f32_16x16x32_bf16(A, f.b3, acc[3], 0, 0, 0);
}

__global__ __launch_bounds__(64) void proj_kernel(const float* __restrict__ x,
                                                  const unsigned short* __restrict__ Wb,
                                                  unsigned short* __restrict__ Ko) {
    const int l = threadIdx.x, lm = l & 15, lg = l >> 4;
    const size_t m0 = (size_t)blockIdx.x * 16;
    const float* xr = x + (m0 + lm) * CDIM + lg * 8;
    const unsigned short* wr = Wb + (size_t)lm * CDIM + lg * 8;

    f32x4 acc[4];
    acc[0] = acc[1] = acc[2] = acc[3] = (f32x4){0.f, 0.f, 0.f, 0.f};

    PF c0 = pload(xr, wr, 0);
    PF c1 = pload(xr, wr, 1);
    #pragma unroll
    for (int ks = 0; ks < 30; ++ks) {
        PF n = pload(xr, wr, ks + 2);
        pstep(c0, acc);
        c0 = c1; c1 = n;
    }
    pstep(c0, acc);
    pstep(c1, acc);

    // D layout: col = lm (head-local), row = lg*4 + r
    #pragma unroll
    for (int nt = 0; nt < 4; ++nt)
        #pragma unroll
        for (int r = 0; r < 4; ++r)
            Ko[(m0 + lg * 4 + r) * HD + nt * 16 + lm] =
                (unsigned short)(pk2(acc[nt][r], 0.f) & 0xffffu);
}

// ---------------- kernel 2: causal flash attention, Q=K=V, MFMA -----------------
struct KT { bf16x8 ka0, ka1, bv0, bv1, bv2, bv3; };

static __device__ __forceinline__ KT load_tile(const unsigned short* __restrict__ Kb,
                                               int kt, int lm, int lg) {
    KT t;
    // QK A-frag (swapped): row = kv-local = lm, k = d = lg*8 + j (+32 for frag 1)
    const unsigned short* ar = Kb + (size_t)(kt * 16 + lm) * HD + lg * 8;
    t.ka0 = *(const bf16x8*)ar;
    t.ka1 = *(const bf16x8*)(ar + 32);
    // PV B-frags: col = d-local = lm (+16n), k-slot j<4 -> kv = lg*4 + j; upper half zero
    const unsigned short* vr = Kb + (size_t)(kt * 16 + lg * 4) * HD + lm;
    {
        unsigned v0 = vr[0], v1 = vr[64], v2 = vr[128], v3 = vr[192];
        i32x4 w = { (int)(v0 | (v1 << 16)), (int)(v2 | (v3 << 16)), 0, 0 };
        t.bv0 = __builtin_bit_cast(bf16x8, w);
    }
    {
        unsigned v0 = vr[16], v1 = vr[80], v2 = vr[144], v3 = vr[208];
        i32x4 w = { (int)(v0 | (v1 << 16)), (int)(v2 | (v3 << 16)), 0, 0 };
        t.bv1 = __builtin_bit_cast(bf16x8, w);
    }
    {
        unsigned v0 = vr[32], v1 = vr[96], v2 = vr[160], v3 = vr[224];
        i32x4 w = { (int)(v0 | (v1 << 16)), (int)(v2 | (v3 << 16)), 0, 0 };
        t.bv2 = __builtin_bit_cast(bf16x8, w);
    }
    {
        unsigned v0 = vr[48], v1 = vr[112], v2 = vr[176], v3 = vr[240];
        i32x4 w = { (int)(v0 | (v1 << 16)), (int)(v2 | (v3 << 16)), 0, 0 };
        t.bv3 = __builtin_bit_cast(bf16x8, w);
    }
    return t;
}

template <bool DIAG>
static __device__ __forceinline__ void proc_tile(const KT& t, bf16x8 bq0, bf16x8 bq1,
                                                 int lm, int lg,
                                                 float& m, float& ls, f32x4 o[4]) {
    f32x4 s4 = (f32x4){0.f, 0.f, 0.f, 0.f};
    s4 = __builtin_amdgcn_mfma_f32_16x16x32_bf16(t.ka0, bq0, s4, 0, 0, 0);
    s4 = __builtin_amdgcn_mfma_f32_16x16x32_bf16(t.ka1, bq1, s4, 0, 0, 0);
    // D: col = lm = q-local, row = lg*4 + r = kv-local   (raw scores, unscaled)
    float s0 = s4[0], s1 = s4[1], s2 = s4[2], s3 = s4[3];
    if (DIAG) {
        const int kb = lg * 4;
        s0 = (kb + 0 > lm) ? -1e30f : s0;
        s1 = (kb + 1 > lm) ? -1e30f : s1;
        s2 = (kb + 2 > lm) ? -1e30f : s2;
        s3 = (kb + 3 > lm) ? -1e30f : s3;
    }
    float pm = fmaxf(fmaxf(s0, s1), fmaxf(s2, s3));
    pm = fmaxf(pm, __shfl_xor(pm, 16));
    pm = fmaxf(pm, __shfl_xor(pm, 32));
    if (__any(pm > m + 256.f)) {   // defer-max: 256 raw = 8 e-folds after scaling
        float mn = fmaxf(m, pm);
        float al = __builtin_amdgcn_exp2f((m - mn) * CEXP);
        m = mn;
        ls *= al;
        float a0 = __shfl(al, lg * 4 + 0);
        float a1 = __shfl(al, lg * 4 + 1);
        float a2 = __shfl(al, lg * 4 + 2);
        float a3 = __shfl(al, lg * 4 + 3);
        #pragma unroll
        for (int n = 0; n < 4; ++n) {
            o[n][0] *= a0; o[n][1] *= a1; o[n][2] *= a2; o[n][3] *= a3;
        }
    }
    const float mC = m * CEXP;
    float p0 = __builtin_amdgcn_exp2f(s0 * CEXP - mC);
    float p1 = __builtin_amdgcn_exp2f(s1 * CEXP - mC);
    float p2 = __builtin_amdgcn_exp2f(s2 * CEXP - mC);
    float p3 = __builtin_amdgcn_exp2f(s3 * CEXP - mC);
    ls += (p0 + p1) + (p2 + p3);
    // P^T A-frag: row = q = lm, k-slot j<4 -> kv = lg*4 + j (matches D rows exactly)
    i32x4 pw = { (int)pk2(p0, p1), (int)pk2(p2, p3), 0, 0 };
    bf16x8 pa = __builtin_bit_cast(bf16x8, pw);
    o[0] = __builtin_amdgcn_mfma_f32_16x16x32_bf16(pa, t.bv0, o[0], 0, 0, 0);
    o[1] = __builtin_amdgcn_mfma_f32_16x16x32_bf16(pa, t.bv1, o[1], 0, 0, 0);
    o[2] = __builtin_amdgcn_mfma_f32_16x16x32_bf16(pa, t.bv2, o[2], 0, 0, 0);
    o[3] = __builtin_amdgcn_mfma_f32_16x16x32_bf16(pa, t.bv3, o[3], 0, 0, 0);
}

// one wave processes kv tiles kt ≡ w (mod 4) of q-tile qt, accumulating partial (m,ls,o)
static __device__ __forceinline__ void flash_qtile(const unsigned short* __restrict__ Kb,
                                                   int qt, int w, int lm, int lg,
                                                   float& m, float& ls, f32x4 o[4]) {
    const unsigned short* qr = Kb + (size_t)(qt * 16 + lm) * HD + lg * 8;
    bf16x8 bq0 = *(const bf16x8*)qr;          // B-frag: col = q-local = lm, k = d
    bf16x8 bq1 = *(const bf16x8*)(qr + 32);
    const int diff = qt - w;
    if (diff < 0) return;
    const int last = qt - (diff & 3);
    KT A = load_tile(Kb, w, lm, lg);
    for (int kt = w; kt < last; kt += 4) {
        KT B = load_tile(Kb, kt + 4, lm, lg);
        proc_tile<false>(A, bq0, bq1, lm, lg, m, ls, o);
        A = B;
    }
    if (last == qt) proc_tile<true>(A, bq0, bq1, lm, lg, m, ls, o);
    else            proc_tile<false>(A, bq0, bq1, lm, lg, m, ls, o);
}

// 512 blocks x 256 threads (4 waves). Block = (batch, causal pair {i, 127-i}).
// Wave w handles kv tiles ≡ w (mod 4) for BOTH q-tiles -> 32.25 tiles/wave, balanced.
__global__ __launch_bounds__(256, 2) void attn_kernel(const unsigned short* __restrict__ K,
                                                      float* __restrict__ out) {
    __shared__ float oS[2][4][16][64];
    __shared__ float mS[2][4][16];
    __shared__ float lS[2][4][16];
    const int tid = threadIdx.x;
    const int wid = tid >> 6, l = tid & 63, lm = l & 15, lg = l >> 4;
    const int b = blockIdx.x >> 6, i = blockIdx.x & 63;
    const unsigned short* Kb = K + (size_t)b * SEQ * HD;

    #pragma unroll
    for (int s = 0; s < 2; ++s) {
        const int qt = s ? (127 - i) : i;
        float m = -INFINITY, ls = 0.f;
        f32x4 o[4];
        o[0] = o[1] = o[2] = o[3] = (f32x4){0.f, 0.f, 0.f, 0.f};
        flash_qtile(Kb, qt, wid, lm, lg, m, ls, o);
        // BUGFIX (round 3): ls is a per-lane partial (this lane's 4 kv-rows per
        // tile); reduce across the 4 lanes sharing q-column lm BEFORE publishing.
        ls += __shfl_xor(ls, 16);
        ls += __shfl_xor(ls, 32);
        #pragma unroll
        for (int nt = 0; nt < 4; ++nt)
            #pragma unroll
            for (int r = 0; r < 4; ++r)
                oS[s][wid][lg * 4 + r][nt * 16 + lm] = o[nt][r];
        if (lg == 0) { mS[s][wid][lm] = m; lS[s][wid][lm] = ls; }
    }
    __syncthreads();

    // combine 4 partials: thread -> (slot, row, 8-col group)
    const int slot = tid >> 7;
    const int row  = (tid >> 3) & 15;
    const int cg   = tid & 7;
    const int qt   = slot ? (127 - i) : i;
    float mw[4], lw[4], cw[4];
    #pragma unroll
    for (int w = 0; w < 4; ++w) { mw[w] = mS[slot][w][row]; lw[w] = lS[slot][w][row]; }
    float mx = fmaxf(fmaxf(mw[0], mw[1]), fmaxf(mw[2], mw[3]));
    float L = 0.f;
    #pragma unroll
    for (int w = 0; w < 4; ++w) {
        cw[w] = __builtin_amdgcn_exp2f((mw[w] - mx) * CEXP);
        L += cw[w] * lw[w];
    }
    const float inv = 1.f / L;
    f32x4 a0 = (f32x4){0.f, 0.f, 0.f, 0.f}, a1 = a0;
    #pragma unroll
    for (int w = 0; w < 4; ++w) {
        f32x4 v0 = *(const f32x4*)&oS[slot][w][row][cg * 8];
        f32x4 v1 = *(const f32x4*)&oS[slot][w][row][cg * 8 + 4];
        a0 += cw[w] * v0;
        a1 += cw[w] * v1;
    }
    float* op = out + ((size_t)b * SEQ + qt * 16 + row) * HD + cg * 8;
    *(f32x4*)op       = a0 * inv;
    *(f32x4*)(op + 4) = a1 * inv;
}

extern "C" void kernel_launch(void* const* d_in, const int* in_sizes, int n_in,
                              void* d_out, int out_size, void* d_ws, size_t ws_size,
                              hipStream_t stream) {
    const float* x  = (const float*)d_in[0];   // [8,2048,1024] fp32
    const float* Wk = (const float*)d_in[1];   // [64,1024] fp32
    float* o        = (float*)d_out;           // [8,2048,64] fp32
    unsigned short* Kp = (unsigned short*)d_ws;              // bf16 K [16384][64] (2 MB)
    unsigned short* Wb = Kp + (size_t)SEQ * 8 * HD;          // bf16 W [64][1024] (128 KB)

    wconv_kernel<<<64, 256, 0, stream>>>(Wk, (unsigned*)Wb);
    proj_kernel<<<1024, 64, 0, stream>>>(x, Wb, Kp);
    attn_kernel<<<512, 256, 0, stream>>>(Kp, o);
}